// Round 4
// baseline (1909.031 us; speedup 1.0000x reference)
//
#include <hip/hip_runtime.h>
#include <hip/hip_bf16.h>

#define DEV __device__ __forceinline__

typedef __attribute__((ext_vector_type(8))) __bf16 bfrag;   // 8 bf16 = 4 VGPRs (A/B frag)
typedef __attribute__((ext_vector_type(4))) float  f32x4;   // C/D frag

DEV f32x4 mfma32(bfrag a, bfrag b, f32x4 c) {
    return __builtin_amdgcn_mfma_f32_16x16x32_bf16(a, b, c, 0, 0, 0);
}

DEV unsigned short to_bf16(float f) {
    union { __bf16 b; unsigned short u; } cv;
    cv.b = (__bf16)f;
    return cv.u;
}

#if defined(__has_builtin)
#if __has_builtin(__builtin_amdgcn_cvt_pk_bf16_f32)
#define HAS_PK_BF16 1
#endif
#endif

DEV unsigned int pk2(float a, float b) {
#ifdef HAS_PK_BF16
    auto r = __builtin_amdgcn_cvt_pk_bf16_f32(a, b);
    unsigned int u;
    __builtin_memcpy(&u, &r, 4);
    return u;
#else
    return (unsigned)to_bf16(a) | ((unsigned)to_bf16(b) << 16);
#endif
}

// pack 4 f32 -> 4 bf16 -> one 8B LDS store
DEV void store4(unsigned short* p, float v0, float v1, float v2, float v3) {
    typedef __attribute__((ext_vector_type(2))) unsigned int uint2v;
    uint2v q;
    q[0] = pk2(v0, v1);
    q[1] = pk2(v2, v3);
    *reinterpret_cast<uint2v*>(p) = q;
}

DEV float fastrcp(float x) { float r; asm("v_rcp_f32 %0, %1" : "=v"(r) : "v"(x)); return r; }

// tanh-form gelu via sigmoid: x*sigmoid(1.5957691x + 0.07135481x^3)
DEV float gelu(float x) {
    float u = x * fmaf(0.07135481f, x * x, 1.5957691f);
    float e = __expf(-u);
    return x * fastrcp(1.0f + e);
}

namespace cfg {
constexpr size_t OFF_ACC  = 0;                                  // 128 f32 bins
constexpr size_t OFF_WQ   = 512;
constexpr size_t SZ_HEAD  = (size_t)48 * 64 * 64 * 2;           // 393216
constexpr size_t OFF_WK   = OFF_WQ + SZ_HEAD;
constexpr size_t OFF_WV   = OFF_WK + SZ_HEAD;
constexpr size_t OFF_WHOO = OFF_WV + SZ_HEAD;                   // fused Wh@Wo per head
constexpr size_t OFF_F1   = OFF_WHOO + SZ_HEAD;                 // 6*208*64 bf16
constexpr size_t OFF_F2   = OFF_F1 + (size_t)6 * 208 * 64 * 2;  // 6*64*224 bf16
constexpr size_t OFF_MF   = OFF_F2 + (size_t)6 * 64 * 224 * 2;  // fused M1@M2 [64][64]
constexpr size_t OFF_PP   = OFF_MF + 8192;
constexpr size_t OFF_POSB = OFF_PP + 8192;                      // 16*64 f32 (pos + patch bias)
constexpr size_t OFF_LN   = OFF_POSB + 4096;                    // 4*384 f32 LN tables
}

// ---------------- prepack kernels ----------------

__global__ void pack_qkv(const float* __restrict__ wq, const float* __restrict__ bq,
                         const float* __restrict__ wk, const float* __restrict__ bk,
                         const float* __restrict__ wv, const float* __restrict__ bv,
                         char* __restrict__ ws)
{
    int id = blockIdx.x * 256 + threadIdx.x;     // 3*48*4096 threads
    int which = id / (48 * 4096);
    int rem   = id % (48 * 4096);
    int lh  = rem >> 12;
    int pos = rem & 4095;
    int n = pos >> 6, k = pos & 63;              // n = out feature, k = in feature
    const float* w = (which == 0) ? wq : (which == 1) ? wk : wv;
    const float* b = (which == 0) ? bq : (which == 1) ? bk : bv;
    float v = 0.f;
    if (n < 49) {
        if (k < 49)       v = w[((size_t)lh * 49 + k) * 49 + n];
        else if (k == 49) v = b[lh * 49 + n];
    }
    unsigned short* dst = (unsigned short*)(ws + cfg::OFF_WQ + (size_t)which * cfg::SZ_HEAD);
    dst[(size_t)lh * 4096 + pos] = to_bf16(v);
}

__global__ void pack_fused(const float* __restrict__ wh, const float* __restrict__ bh,
                           const float* __restrict__ wo, const float* __restrict__ bo,
                           const float* __restrict__ m1, const float* __restrict__ m1b,
                           const float* __restrict__ m2, const float* __restrict__ m2b,
                           char* __restrict__ ws)
{
    int id = blockIdx.x * 256 + threadIdx.x;     // 48*4096 + 4096 threads
    if (id < 48 * 4096) {
        int lh = id >> 12, pos = id & 4095;
        int l = lh >> 3, h = lh & 7;
        int d = pos >> 6, e = pos & 63;
        float s = 0.f;
        if (d < 49) {
            if (e < 49) {
                for (int o = 0; o < 49; ++o)
                    s += wh[((size_t)lh * 49 + e) * 49 + o] * wo[((size_t)l * 392 + h * 49 + o) * 49 + d];
            } else if (e == 49) {
                for (int o = 0; o < 49; ++o)
                    s += bh[lh * 49 + o] * wo[((size_t)l * 392 + h * 49 + o) * 49 + d];
                s += bo[l * 49 + d] * 0.125f;
            }
        }
        ((unsigned short*)(ws + cfg::OFF_WHOO))[(size_t)lh * 4096 + d * 64 + e] = to_bf16(s);
        return;
    }
    id -= 48 * 4096;
    if (id < 4096) {
        int d = id >> 6, e = id & 63;
        float s = 0.f;
        if (d < 49) {
            if (e < 49) {
                for (int o = 0; o < 49; ++o) s += m1[e * 49 + o] * m2[o * 49 + d];
            } else if (e == 49) {
                for (int o = 0; o < 49; ++o) s += m1b[o] * m2[o * 49 + d];
                s += m2b[d];
            }
        }
        ((unsigned short*)(ws + cfg::OFF_MF))[d * 64 + e] = to_bf16(s);
    }
}

__global__ void pack_rest(const float* __restrict__ f1w, const float* __restrict__ f1b,
                          const float* __restrict__ f2w, const float* __restrict__ f2b,
                          const float* __restrict__ ppw, const float* __restrict__ ppb,
                          const float* __restrict__ pos, char* __restrict__ ws)
{
    int id = blockIdx.x * 256 + threadIdx.x;
    if (id < 6 * 208 * 64) {                                    // FFN1: [l][n=208][k=64], k49=bias
        int l = id / (208 * 64), rem = id % (208 * 64), n = rem / 64, k = rem % 64;
        float v = 0.f;
        if (n < 196) {
            if (k < 49)       v = f1w[((size_t)l * 49 + k) * 196 + n];
            else if (k == 49) v = f1b[l * 196 + n];
        }
        ((unsigned short*)(ws + cfg::OFF_F1))[id] = to_bf16(v);
        return;
    }
    id -= 6 * 208 * 64;
    if (id < 6 * 64 * 224) {                                    // FFN2: [l][n=64][k=224], k196=bias
        int l = id / (64 * 224), rem = id % (64 * 224), n = rem / 224, k = rem % 224;
        float v = 0.f;
        if (n < 49) {
            if (k < 196)       v = f2w[((size_t)l * 196 + k) * 49 + n];
            else if (k == 196) v = f2b[l * 49 + n];
        }
        ((unsigned short*)(ws + cfg::OFF_F2))[id] = to_bf16(v);
        return;
    }
    id -= 6 * 64 * 224;
    if (id < 4096) {                                            // patch proj [n][k]
        int n = id >> 6, k = id & 63;
        ((unsigned short*)(ws + cfg::OFF_PP))[id] = to_bf16((n < 49 && k < 49) ? ppw[k * 49 + n] : 0.f);
        return;
    }
    id -= 4096;
    if (id < 1024) {                                            // posb[p][e]
        int p = id >> 6, e = id & 63;
        ((float*)(ws + cfg::OFF_POSB))[id] = (e < 49) ? pos[p * 49 + e] + ppb[e] : 0.f;
        return;
    }
    id -= 1024;
    if (id < 128) ((float*)(ws + cfg::OFF_ACC))[id] = 0.f;
}

__global__ void pack_ln(const float* __restrict__ ln1w, const float* __restrict__ ln1b,
                        const float* __restrict__ ln2w, const float* __restrict__ ln2b,
                        char* __restrict__ ws)
{
    int id = blockIdx.x * 256 + threadIdx.x;     // 1536 threads
    if (id >= 1536) return;
    int which = id / 384, r = id % 384, l = r >> 6, f = r & 63;
    const float* s = (which == 0) ? ln1w : (which == 1) ? ln1b : (which == 2) ? ln2w : ln2b;
    float v = (f < 49) ? s[l * 49 + f] : 0.f;
    ((float*)(ws + cfg::OFF_LN))[which * 384 + r] = v;
}

// ---------------- main fused kernel ----------------
// Cooperative pair: 2 waves/block, 2 elements/block.
// Wave w owns output-feature half mt in {2w, 2w+1} of every weight GEMM;
// S/softmax/PV split by element (wave w handles element u=w).
// LN statistics exchanged cross-wave via 512B f32 scratch in dead K-tile.

__global__ __launch_bounds__(128, 4)
void vit_main(const float* __restrict__ x, const int* __restrict__ trg,
              const float* __restrict__ cw1, const float* __restrict__ cb1,
              const float* __restrict__ cw2, const float* __restrict__ cb2,
              char* __restrict__ ws)
{
    constexpr int S64 = 72;           // [16][64] tile stride (ushorts)
    constexpr int SV  = 40;           // VT [52][32] stride
    constexpr int SP  = 40;           // P  [16][32] stride
    constexpr int SM  = 224;          // MID [16][224] stride (exact, no pad)
    constexpr int TA = 0, TB = 1152, TV = 2304, TP = 4384, MIDO = 1440, EL = 5024;
    constexpr int SCRO = 1152;        // abs ushort offset of f32 scratch (TB-u0 rows 0..3)
    __shared__ unsigned short sm[2 * EL];   // 20096 B -> 8 blocks/CU, 16 waves/CU

    const int tid  = threadIdx.x;
    const int w    = tid >> 6;        // wave id 0/1
    const int lane = tid & 63;
    const int g = lane >> 4, c = lane & 15;
    const int mtw = 2 * w;            // owned mt base (features 32w..32w+31)
    const long e0 = (long)blockIdx.x * 2;
    const f32x4 FZ = {0.f, 0.f, 0.f, 0.f};

    const unsigned short* WQ = (const unsigned short*)(ws + cfg::OFF_WQ);
    const unsigned short* WK = (const unsigned short*)(ws + cfg::OFF_WK);
    const unsigned short* WV = (const unsigned short*)(ws + cfg::OFF_WV);
    const unsigned short* WHOO = (const unsigned short*)(ws + cfg::OFF_WHOO);
    const unsigned short* F1 = (const unsigned short*)(ws + cfg::OFF_F1);
    const unsigned short* F2 = (const unsigned short*)(ws + cfg::OFF_F2);
    const unsigned short* MF = (const unsigned short*)(ws + cfg::OFF_MF);
    const unsigned short* PP = (const unsigned short*)(ws + cfg::OFF_PP);
    const float* POSB  = (const float*)(ws + cfg::OFF_POSB);
    const float* LNT   = (const float*)(ws + cfg::OFF_LN);     // [4][384]
    float* ACC = (float*)(ws + cfg::OFF_ACC);
    float* scr = reinterpret_cast<float*>(&sm[SCRO]);          // 128 f32

    // ---- stage x: wave w stages element u=w -> TA-uw
    {
        const float* xb = x + (e0 + w) * 784;
        #pragma unroll
        for (int it = 0; it < 8; ++it) {
            int i = it * 64 + lane;
            int p = i >> 5, ee = (i & 31) * 2;
            float v0 = (ee < 49) ? xb[p * 49 + ee] : 0.f;
            float v1 = (ee + 1 < 49) ? xb[p * 49 + ee + 1] : 0.f;
            *reinterpret_cast<unsigned int*>(&sm[w * EL + TA + p * S64 + ee]) = pk2(v0, v1);
        }
    }
    __syncthreads();                                            // x staged

    bfrag a_h[2][2];
    auto loadB = [&](int off, bfrag (&af)[2][2]) {
        #pragma unroll
        for (int u = 0; u < 2; ++u)
            #pragma unroll
            for (int kk = 0; kk < 2; ++kk)
                af[u][kk] = *(const bfrag*)&sm[u * EL + off + c * S64 + kk * 32 + g * 8];
    };
    loadB(TA, a_h);

    // ---- patch proj (own mt, both u) + posb
    f32x4 hreg[2][2];
    #pragma unroll
    for (int j = 0; j < 2; ++j) {
        const int mt = mtw + j;
        f32x4 t0 = FZ, t1 = FZ;
        #pragma unroll
        for (int kk = 0; kk < 2; ++kk) {
            bfrag wf = *(const bfrag*)&PP[(mt * 16 + c) * 64 + kk * 32 + g * 8];
            t0 = mfma32(wf, a_h[0][kk], t0);
            t1 = mfma32(wf, a_h[1][kk], t1);
        }
        f32x4 pb = *(const f32x4*)&POSB[c * 64 + mt * 16 + 4 * g];
        hreg[0][j] = t0 + pb;
        hreg[1][j] = t1 + pb;
    }

    f32x4 yreg[2][2];

    // =================== layer loop ===================
    for (int l = 0; l < 6; ++l) {
        __syncthreads();                                        // A1: prior TA readers done
        // stage h (own mt, both u) + slot49 (wave1); zero VT/P pads (u=w)
        #pragma unroll
        for (int u = 0; u < 2; ++u)
            #pragma unroll
            for (int j = 0; j < 2; ++j)
                store4(&sm[u * EL + TA + c * S64 + (mtw + j) * 16 + 4 * g],
                       hreg[u][j][0], hreg[u][j][1], hreg[u][j][2], hreg[u][j][3]);
        if (w == 1 && lane < 32)
            sm[(lane >> 4) * EL + TA + (lane & 15) * S64 + 49] = 0x3F80;
        *(f32x4*)&sm[w * EL + TV + lane * SV + 16] = FZ;
        *(f32x4*)&sm[w * EL + TV + lane * SV + 24] = FZ;
        if (lane < 4) {
            *(f32x4*)&sm[w * EL + TV + (64 + lane) * SV + 16] = FZ;
            *(f32x4*)&sm[w * EL + TV + (64 + lane) * SV + 24] = FZ;
        }
        __syncthreads();                                        // A2: h full, pads zeroed
        loadB(TA, a_h);

        f32x4 oacc[2][2];
        #pragma unroll
        for (int u = 0; u < 2; ++u)
            #pragma unroll
            for (int j = 0; j < 2; ++j) oacc[u][j] = FZ;

        // ---------- attention heads ----------
        for (int hh = 0; hh < 8; ++hh) {
            const int lh = l * 8 + hh;
            const unsigned short* wq = WQ + (size_t)lh * 4096;
            const unsigned short* wk = WK + (size_t)lh * 4096;
            const unsigned short* wv = WV + (size_t)lh * 4096;
            const unsigned short* who = WHOO + (size_t)lh * 4096;

            __syncthreads();                                    // D: a_h loads / prev ao reads done
            // Q -> TA, K -> TB (own mt, both u)
            #pragma unroll
            for (int j = 0; j < 2; ++j) {
                const int mt = mtw + j;
                f32x4 q0 = FZ, q1 = FZ, k0 = FZ, k1 = FZ;
                #pragma unroll
                for (int kk = 0; kk < 2; ++kk) {
                    bfrag wqf = *(const bfrag*)&wq[(mt * 16 + c) * 64 + kk * 32 + g * 8];
                    bfrag wkf = *(const bfrag*)&wk[(mt * 16 + c) * 64 + kk * 32 + g * 8];
                    q0 = mfma32(wqf, a_h[0][kk], q0);
                    q1 = mfma32(wqf, a_h[1][kk], q1);
                    k0 = mfma32(wkf, a_h[0][kk], k0);
                    k1 = mfma32(wkf, a_h[1][kk], k1);
                }
                store4(&sm[0 * EL + TA + c * S64 + mt * 16 + 4 * g], q0[0], q0[1], q0[2], q0[3]);
                store4(&sm[1 * EL + TA + c * S64 + mt * 16 + 4 * g], q1[0], q1[1], q1[2], q1[3]);
                store4(&sm[0 * EL + TB + c * S64 + mt * 16 + 4 * g], k0[0], k0[1], k0[2], k0[3]);
                store4(&sm[1 * EL + TB + c * S64 + mt * 16 + 4 * g], k1[0], k1[1], k1[2], k1[3]);
            }
            // V (normal orientation) -> VT [e][tok] (own nt, both u); rows>=52 spill = zeros into P rows 0..11
            #pragma unroll
            for (int j = 0; j < 2; ++j) {
                const int nt = mtw + j;
                f32x4 v0 = FZ, v1 = FZ;
                #pragma unroll
                for (int kk = 0; kk < 2; ++kk) {
                    bfrag wvf = *(const bfrag*)&wv[(nt * 16 + c) * 64 + kk * 32 + g * 8];
                    v0 = mfma32(a_h[0][kk], wvf, v0);
                    v1 = mfma32(a_h[1][kk], wvf, v1);
                }
                store4(&sm[0 * EL + TV + (nt * 16 + c) * SV + 4 * g], v0[0], v0[1], v0[2], v0[3]);
                store4(&sm[1 * EL + TV + (nt * 16 + c) * SV + 4 * g], v1[0], v1[1], v1[2], v1[3]);
            }
            __syncthreads();                                    // B: Q,K,V full

            // S^T + softmax + P store  (wave w handles u=w only)
            {
                f32x4 sc = FZ;
                #pragma unroll
                for (int kk = 0; kk < 2; ++kk) {
                    bfrag akf = *(const bfrag*)&sm[w * EL + TB + c * S64 + kk * 32 + g * 8];
                    bfrag aqf = *(const bfrag*)&sm[w * EL + TA + c * S64 + kk * 32 + g * 8];
                    sc = mfma32(akf, aqf, sc);
                }
                float s0 = sc[0] * (1.f / 7.f), s1 = sc[1] * (1.f / 7.f);
                float s2 = sc[2] * (1.f / 7.f), s3 = sc[3] * (1.f / 7.f);
                float m = fmaxf(fmaxf(s0, s1), fmaxf(s2, s3));
                m = fmaxf(m, __shfl_xor(m, 16));
                m = fmaxf(m, __shfl_xor(m, 32));
                float p0 = __expf(s0 - m), p1 = __expf(s1 - m);
                float p2 = __expf(s2 - m), p3 = __expf(s3 - m);
                float t = p0 + p1 + p2 + p3;
                t += __shfl_xor(t, 16);
                t += __shfl_xor(t, 32);
                float inv = fastrcp(t);
                store4(&sm[w * EL + TP + c * SP + 4 * g], p0 * inv, p1 * inv, p2 * inv, p3 * inv);
            }
            // PV -> ao (full width, u=w) + slot49
            {
                bfrag bp = *(const bfrag*)&sm[w * EL + TP + c * SP + g * 8];
                #pragma unroll
                for (int mt2 = 0; mt2 < 4; ++mt2) {
                    bfrag av = *(const bfrag*)&sm[w * EL + TV + (mt2 * 16 + c) * SV + g * 8];
                    f32x4 o = mfma32(av, bp, FZ);
                    store4(&sm[w * EL + TA + c * S64 + mt2 * 16 + 4 * g], o[0], o[1], o[2], o[3]);
                }
                if (lane < 16) sm[w * EL + TA + lane * S64 + 49] = 0x3F80;
            }
            __syncthreads();                                    // C: ao full both u

            // Whoo accumulate (own mt, both u)
            {
                bfrag ab[2][2];
                loadB(TA, ab);
                #pragma unroll
                for (int j = 0; j < 2; ++j)
                    #pragma unroll
                    for (int kk = 0; kk < 2; ++kk) {
                        bfrag wf = *(const bfrag*)&who[((mtw + j) * 16 + c) * 64 + kk * 32 + g * 8];
                        oacc[0][j] = mfma32(wf, ab[0][kk], oacc[0][j]);
                        oacc[1][j] = mfma32(wf, ab[1][kk], oacc[1][j]);
                    }
            }
        } // heads

        // ---------- LN1 ----------
        float z1[2][2][4], sP[2], qP[2];
        #pragma unroll
        for (int u = 0; u < 2; ++u) {
            float s = 0.f, q2 = 0.f;
            #pragma unroll
            for (int j = 0; j < 2; ++j)
                #pragma unroll
                for (int r = 0; r < 4; ++r) {
                    float zz = hreg[u][j][r] + oacc[u][j][r];
                    z1[u][j][r] = zz;
                    s += zz;
                    q2 += zz * zz;
                }
            s += __shfl_xor(s, 16); s += __shfl_xor(s, 32);
            q2 += __shfl_xor(q2, 16); q2 += __shfl_xor(q2, 32);
            sP[u] = s; qP[u] = q2;
        }
        if (w == 0 && g == 0) {
            scr[(0 * 16 + c) * 2 + 0] = sP[0]; scr[(0 * 16 + c) * 2 + 1] = qP[0];
            scr[(1 * 16 + c) * 2 + 0] = sP[1]; scr[(1 * 16 + c) * 2 + 1] = qP[1];
        }
        __syncthreads();                                        // E1
        float sT[2], qT[2];
        if (w == 1) {
            #pragma unroll
            for (int u = 0; u < 2; ++u) {
                sT[u] = sP[u] + scr[(u * 16 + c) * 2 + 0];
                qT[u] = qP[u] + scr[(u * 16 + c) * 2 + 1];
            }
            if (g == 0) {
                scr[64 + (0 * 16 + c) * 2 + 0] = sT[0]; scr[64 + (0 * 16 + c) * 2 + 1] = qT[0];
                scr[64 + (1 * 16 + c) * 2 + 0] = sT[1]; scr[64 + (1 * 16 + c) * 2 + 1] = qT[1];
            }
        }
        __syncthreads();                                        // E2
        if (w == 0) {
            #pragma unroll
            for (int u = 0; u < 2; ++u) {
                sT[u] = scr[64 + (u * 16 + c) * 2 + 0];
                qT[u] = scr[64 + (u * 16 + c) * 2 + 1];
            }
        }
        #pragma unroll
        for (int u = 0; u < 2; ++u) {
            float mu = sT[u] * (1.f / 49.f);
            float var = qT[u] * (1.f / 49.f) - mu * mu;
            float rstd = rsqrtf(var + 1e-5f);
            #pragma unroll
            for (int j = 0; j < 2; ++j) {
                f32x4 lwv = *(const f32x4*)&LNT[0 * 384 + l * 64 + (mtw + j) * 16 + 4 * g];
                f32x4 lbv = *(const f32x4*)&LNT[1 * 384 + l * 64 + (mtw + j) * 16 + 4 * g];
                #pragma unroll
                for (int r = 0; r < 4; ++r)
                    yreg[u][j][r] = (z1[u][j][r] - mu) * rstd * lwv[r] + lbv[r];
                store4(&sm[u * EL + TA + c * S64 + (mtw + j) * 16 + 4 * g],
                       yreg[u][j][0], yreg[u][j][1], yreg[u][j][2], yreg[u][j][3]);
            }
        }
        if (w == 1 && lane < 32)
            sm[(lane >> 4) * EL + TA + (lane & 15) * S64 + 49] = 0x3F80;
        __syncthreads();                                        // F: y full

        // ---------- FFN1: mid = gelu(y W1) -> MID (mt-split) ----------
        {
            bfrag ay[2][2];
            loadB(TA, ay);
            // zero MID pad cols 208..223 (u = w)
            *(unsigned long long*)&sm[w * EL + MIDO + (lane >> 2) * SM + 208 + (lane & 3) * 4] = 0ULL;
            const unsigned short* F1l = F1 + (size_t)l * 208 * 64;
            const int m0 = w ? 7 : 0, m1 = w ? 13 : 7;
            for (int mt = m0; mt < m1; ++mt) {
                f32x4 a0 = FZ, a1 = FZ;
                #pragma unroll
                for (int kk = 0; kk < 2; ++kk) {
                    bfrag wf = *(const bfrag*)&F1l[(mt * 16 + c) * 64 + kk * 32 + g * 8];
                    a0 = mfma32(wf, ay[0][kk], a0);
                    a1 = mfma32(wf, ay[1][kk], a1);
                }
                store4(&sm[0 * EL + MIDO + c * SM + mt * 16 + 4 * g],
                       gelu(a0[0]), gelu(a0[1]), gelu(a0[2]), gelu(a0[3]));
                store4(&sm[1 * EL + MIDO + c * SM + mt * 16 + 4 * g],
                       gelu(a1[0]), gelu(a1[1]), gelu(a1[2]), gelu(a1[3]));
            }
            if (w == 1 && lane < 32)
                sm[(lane >> 4) * EL + MIDO + (lane & 15) * SM + 196] = 0x3F80;
        }
        __syncthreads();                                        // G: MID full

        // ---------- FFN2 (own mt, both u) ----------
        f32x4 zac[2][2];
        for (int u = 0; u < 2; ++u) {
            bfrag am[7];
            #pragma unroll
            for (int kk = 0; kk < 7; ++kk)
                am[kk] = *(const bfrag*)&sm[u * EL + MIDO + c * SM + kk * 32 + g * 8];
            const unsigned short* F2l = F2 + (size_t)l * 64 * 224;
            #pragma unroll
            for (int j = 0; j < 2; ++j) {
                f32x4 t = FZ;
                #pragma unroll
                for (int kk = 0; kk < 7; ++kk) {
                    bfrag wf = *(const bfrag*)&F2l[((mtw + j) * 16 + c) * 224 + kk * 32 + g * 8];
                    t = mfma32(wf, am[kk], t);
                }
                zac[u][j] = t;
            }
        }
        // ---------- LN2 ----------
        #pragma unroll
        for (int u = 0; u < 2; ++u) {
            float s = 0.f, q2 = 0.f;
            #pragma unroll
            for (int j = 0; j < 2; ++j)
                #pragma unroll
                for (int r = 0; r < 4; ++r) {
                    float zz = yreg[u][j][r] + zac[u][j][r];
                    z1[u][j][r] = zz;
                    s += zz;
                    q2 += zz * zz;
                }
            s += __shfl_xor(s, 16); s += __shfl_xor(s, 32);
            q2 += __shfl_xor(q2, 16); q2 += __shfl_xor(q2, 32);
            sP[u] = s; qP[u] = q2;
        }
        if (w == 0 && g == 0) {
            scr[(0 * 16 + c) * 2 + 0] = sP[0]; scr[(0 * 16 + c) * 2 + 1] = qP[0];
            scr[(1 * 16 + c) * 2 + 0] = sP[1]; scr[(1 * 16 + c) * 2 + 1] = qP[1];
        }
        __syncthreads();                                        // H1
        if (w == 1) {
            #pragma unroll
            for (int u = 0; u < 2; ++u) {
                sT[u] = sP[u] + scr[(u * 16 + c) * 2 + 0];
                qT[u] = qP[u] + scr[(u * 16 + c) * 2 + 1];
            }
            if (g == 0) {
                scr[64 + (0 * 16 + c) * 2 + 0] = sT[0]; scr[64 + (0 * 16 + c) * 2 + 1] = qT[0];
                scr[64 + (1 * 16 + c) * 2 + 0] = sT[1]; scr[64 + (1 * 16 + c) * 2 + 1] = qT[1];
            }
        }
        __syncthreads();                                        // H2
        if (w == 0) {
            #pragma unroll
            for (int u = 0; u < 2; ++u) {
                sT[u] = scr[64 + (u * 16 + c) * 2 + 0];
                qT[u] = scr[64 + (u * 16 + c) * 2 + 1];
            }
        }
        #pragma unroll
        for (int u = 0; u < 2; ++u) {
            float mu = sT[u] * (1.f / 49.f);
            float var = qT[u] * (1.f / 49.f) - mu * mu;
            float rstd = rsqrtf(var + 1e-5f);
            #pragma unroll
            for (int j = 0; j < 2; ++j) {
                f32x4 lwv = *(const f32x4*)&LNT[2 * 384 + l * 64 + (mtw + j) * 16 + 4 * g];
                f32x4 lbv = *(const f32x4*)&LNT[3 * 384 + l * 64 + (mtw + j) * 16 + 4 * g];
                f32x4 hn;
                #pragma unroll
                for (int r = 0; r < 4; ++r)
                    hn[r] = (z1[u][j][r] - mu) * rstd * lwv[r] + lbv[r];
                hreg[u][j] = hn;
                store4(&sm[u * EL + TA + c * S64 + (mtw + j) * 16 + 4 * g],
                       hn[0], hn[1], hn[2], hn[3]);
            }
        }
        if (w == 1 && lane < 32)
            sm[(lane >> 4) * EL + TA + (lane & 15) * S64 + 49] = 0x3F80;
        __syncthreads();                                        // I: hn full

        // ---------- inter-block MLP (fused M1@M2, own mt, both u) ----------
        {
            bfrag an[2][2];
            loadB(TA, an);
            #pragma unroll
            for (int j = 0; j < 2; ++j) {
                f32x4 t0 = FZ, t1 = FZ;
                #pragma unroll
                for (int kk = 0; kk < 2; ++kk) {
                    bfrag wf = *(const bfrag*)&MF[((mtw + j) * 16 + c) * 64 + kk * 32 + g * 8];
                    t0 = mfma32(wf, an[0][kk], t0);
                    t1 = mfma32(wf, an[1][kk], t1);
                }
                hreg[0][j] = t0;
                hreg[1][j] = t1;
            }
        }
    } // layers

    // =================== pooling + classifier + loss ===================
    __syncthreads();                                            // MLP reads done
    #pragma unroll
    for (int u = 0; u < 2; ++u)
        #pragma unroll
        for (int j = 0; j < 2; ++j)
            store4(&sm[u * EL + TA + c * S64 + (mtw + j) * 16 + 4 * g],
                   hreg[u][j][0], hreg[u][j][1], hreg[u][j][2], hreg[u][j][3]);
    __syncthreads();                                            // final h full

    // wave w handles element u=w entirely
    {
        float s = 0.f;
        #pragma unroll
        for (int p = 0; p < 16; ++p)
            s += (float)(*reinterpret_cast<const __bf16*>(&sm[w * EL + TA + p * S64 + lane]));
        float* pf = reinterpret_cast<float*>(&sm[w * EL + TV]);
        pf[lane] = s * (1.f / 16.f);
        if (lane < 25) {
            float t = cb1[lane];
            for (int d2 = 0; d2 < 49; ++d2) t += pf[d2] * cw1[d2 * 25 + lane];
            pf[64 + lane] = t;
        }
        if (lane < 10) {
            float t2 = cb2[lane];
            for (int k2 = 0; k2 < 25; ++k2) t2 += pf[64 + k2] * cw2[k2 * 10 + lane];
            pf[96 + lane] = t2;
        }
        if (lane == 0) {
            float m = pf[96]; int am_ = 0;
            for (int j = 1; j < 10; ++j) if (pf[96 + j] > m) { m = pf[96 + j]; am_ = j; }
            float se = 0.f;
            for (int j = 0; j < 10; ++j) se += __expf(pf[96 + j] - m);
            float logZ = m + logf(se);
            int t = trg[e0 + w];
            int bin = blockIdx.x & 63;
            atomicAdd(&ACC[bin * 2 + 0], logZ - pf[96 + t]);
            atomicAdd(&ACC[bin * 2 + 1], (am_ == t) ? 1.f : 0.f);
        }
    }
}

__global__ void finalize_k(const char* __restrict__ ws, float* __restrict__ out)
{
    const float* ACC = (const float*)(ws + cfg::OFF_ACC);
    int lane = threadIdx.x;
    float a = ACC[lane * 2 + 0];
    float b = ACC[lane * 2 + 1];
    for (int m = 1; m < 64; m <<= 1) {
        a += __shfl_xor(a, m);
        b += __shfl_xor(b, m);
    }
    if (lane == 0) {
        out[0] = a * (1.f / 16384.f);
        out[1] = b * (1.f / 16384.f);
    }
}

// ---------------- host launcher ----------------

extern "C" void kernel_launch(void* const* d_in, const int* in_sizes, int n_in,
                              void* d_out, int out_size, void* d_ws, size_t ws_size,
                              hipStream_t stream)
{
    const float* x    = (const float*)d_in[0];
    const int*   trg  = (const int*)  d_in[1];
    const float* ppw  = (const float*)d_in[2];
    const float* ppb  = (const float*)d_in[3];
    const float* pos  = (const float*)d_in[4];
    const float* wq   = (const float*)d_in[5];
    const float* bq   = (const float*)d_in[6];
    const float* wk   = (const float*)d_in[7];
    const float* bk   = (const float*)d_in[8];
    const float* wv   = (const float*)d_in[9];
    const float* bv   = (const float*)d_in[10];
    const float* wh   = (const float*)d_in[11];
    const float* bh   = (const float*)d_in[12];
    const float* wo   = (const float*)d_in[13];
    const float* bo   = (const float*)d_in[14];
    const float* ln1w = (const float*)d_in[15];
    const float* ln1b = (const float*)d_in[16];
    const float* ln2w = (const float*)d_in[17];
    const float* ln2b = (const float*)d_in[18];
    const float* f1w  = (const float*)d_in[19];
    const float* f1b  = (const float*)d_in[20];
    const float* f2w  = (const float*)d_in[21];
    const float* f2b  = (const float*)d_in[22];
    const float* m1w  = (const float*)d_in[23];
    const float* m1b  = (const float*)d_in[24];
    const float* m2w  = (const float*)d_in[25];
    const float* m2b  = (const float*)d_in[26];
    const float* cw1  = (const float*)d_in[27];
    const float* cb1  = (const float*)d_in[28];
    const float* cw2  = (const float*)d_in[29];
    const float* cb2  = (const float*)d_in[30];
    char* ws = (char*)d_ws;

    pack_qkv<<<2304, 256, 0, stream>>>(wq, bq, wk, bk, wv, bv, ws);
    pack_fused<<<784, 256, 0, stream>>>(wh, bh, wo, bo, m1w, m1b, m2w, m2b, ws);
    pack_rest<<<669, 256, 0, stream>>>(f1w, f1b, f2w, f2b, ppw, ppb, pos, ws);
    pack_ln<<<6, 256, 0, stream>>>(ln1w, ln1b, ln2w, ln2b, ws);
    vit_main<<<8192, 128, 0, stream>>>(x, trg, cw1, cb1, cw2, cb2, ws);
    finalize_k<<<1, 64, 0, stream>>>(ws, (float*)d_out);
}